// Round 5
// baseline (189.907 us; speedup 1.0000x reference)
//
#include <hip/hip_runtime.h>

// LSTM: B=4096, T=256, I=8, H=32, O=1, fp32 in/out, bf16 MFMA compute.
// R10 = R7 skeleton (8 waves, 1 (j,batch) value/lane — the best-measured
// chain) with the x-LDS subsystem DELETED:
//  - x(t+1) comes from 2-step-ahead global float4 prefetch (all lanes load
//    row row0+L; 4-way lane redundancy coalesces in L1). Converted in-reg
//    with the same pack_bf2 rounding as R7's staging -> bit-identical math.
//  - __syncthreads() replaced by {s_waitcnt lgkmcnt(0); s_barrier} so the
//    in-flight global loads are NOT drained at the barrier (compiler's
//    __syncthreads emits vmcnt(0) which would serialize the prefetch).
//  - LDS now holds ONLY the h exchange (2.5 KB): per wave per step one b16
//    write + one b128 read. Theory: R7's ~500-cyc/step stall is partly the
//    CU-shared LDS unit queueing 8 waves x {hfrag + xfrag + stage} ops;
//    removing the x ops relieves the post-barrier queue.
// j-mapping unchanged from R7: wave w owns j = 4w + q via weight-row perm
// fr -> n = 32*(fr&3) + 4w + (fr>>2) (weights are the MFMA FIRST operand);
// lane (q,L) accum reg r = gate r at (m=L, j=4w+q). Gate-g rows pre-scaled
// by 2*log2e (others log2e): 5 exp2 + 3 rcp per value.

#define T_LEN   256
#define LOG2E   1.4426950408889634f

typedef short bf16x8 __attribute__((ext_vector_type(8)));
typedef float f32x4  __attribute__((ext_vector_type(4)));
typedef unsigned u32x4 __attribute__((ext_vector_type(4)));

static __device__ inline short f2bf_rne(float f) {          // one-time (weights)
    union { float f; unsigned u; } v; v.f = f;
    unsigned u = v.u;
    return (short)((u + 0x7FFFu + ((u >> 16) & 1u)) >> 16);
}
static __device__ inline short f2bf_fast(float f) {         // round-half-up
    union { float f; unsigned u; } v; v.f = f;
    return (short)((v.u + 0x8000u) >> 16);
}
static __device__ inline unsigned pack_bf2(float a, float b) {  // low=a, high=b
    union { float f; unsigned u; } x, y; x.f = a; y.f = b;
    return ((x.u + 0x8000u) >> 16) | ((y.u + 0x8000u) & 0xFFFF0000u);
}
static __device__ inline float bf2f(short s) {
    union { unsigned u; float f; } v;
    v.u = ((unsigned)(unsigned short)s) << 16;
    return v.f;
}

__global__ __launch_bounds__(512, 2) void lstm_kernel(
    const float* __restrict__ x, const float* __restrict__ W_ih,
    const float* __restrict__ W_hh, const float* __restrict__ b_ih,
    const float* __restrict__ b_hh, const float* __restrict__ W_out,
    const float* __restrict__ b_out, float* __restrict__ out)
{
    // h double buffer ONLY: [buf][m(0..15)][k(0..31)] bf16, row stride 40
    // shorts. b128 read spans: lanes (q,L) start dword 20L+4q; L and L+8
    // alias the same banks (2-way = free), otherwise disjoint.
    __shared__ __attribute__((aligned(16))) short h_lds[2][16 * 40];

    const int tid  = threadIdx.x;
    const int w    = tid >> 6;        // wave 0..7 -> owns j = 4w + q
    const int lane = tid & 63;
    const int L    = lane & 15;       // batch row within tile / frag row
    const int q    = lane >> 4;       // quad
    const int row0 = blockIdx.x * 16;

    // ---- one-time: weight fragments (FIRST-operand layout [row=L][k=8q+j]) ----
    // row fr=L holds W row n = 32*(L&3) + 4w + (L>>2); gate = L&3,
    // scaled by log2e (gate-g rows: 2*log2e, folding tanh's factor 2).
    const int   n  = 32 * (L & 3) + 4 * w + (L >> 2);
    const float sc = ((L & 3) == 2 ? 2.f * LOG2E : LOG2E);
    bf16x8 whh_f, wih_f = (bf16x8){0,0,0,0,0,0,0,0};
    {
        const float* src = W_hh + n * 32 + q * 8;
#pragma unroll
        for (int j = 0; j < 8; ++j) whh_f[j] = f2bf_rne(src[j] * sc);
        if (q == 0) {                              // only k=0..7 exist (I=8)
            const float* s2 = W_ih + n * 8;
#pragma unroll
            for (int j = 0; j < 8; ++j) wih_f[j] = f2bf_rne(s2[j] * sc);
        }
    }
    // bias in C-layout: reg r -> row fr=4q+r -> n_r = 32r + 4w + q
    f32x4 bias;
#pragma unroll
    for (int r = 0; r < 4; ++r) {
        const int   nr = 32 * r + 4 * w + q;
        const float sr = (r == 2 ? 2.f * LOG2E : LOG2E);
        bias[r] = (b_ih[nr] + b_hh[nr]) * sr;
    }

    // zero h(0) buffer
    for (int i = tid; i < 16 * 40; i += 512) h_lds[0][i] = 0;

    // ---- x prefetch pipeline: this lane always reads batch row row0+L ----
    // (all 4 q-copies load the same 32B -> wave coalesces to 16 unique lines;
    //  q>0 lanes' B-frag slots face zeroed wih rows, any finite value is OK)
    const float4* xbase = (const float4*)x + (size_t)(row0 + L) * (T_LEN * 2);
    float4 ra = xbase[0], rb = xbase[1];          // x(0)

    __syncthreads();   // h(0) visible (full drain OK — prologue only)

    // zx(0) from x(0)
    f32x4 zx;
    {
        u32x4 u;
        u[0] = pack_bf2(ra.x, ra.y); u[1] = pack_bf2(ra.z, ra.w);
        u[2] = pack_bf2(rb.x, rb.y); u[3] = pack_bf2(rb.z, rb.w);
        const bf16x8 xf0 = *(const bf16x8*)&u;
        zx = __builtin_amdgcn_mfma_f32_16x16x32_bf16(wih_f, xf0, bias, 0, 0, 0);
    }
    ra = xbase[2]; rb = xbase[3];                 // x(1) in flight

    float c = 0.f;
    const int hw_off = 4 * w + q;      // this lane's j

#pragma unroll 2
    for (int t = 0; t < T_LEN; ++t) {
        const int par = t & 1, nxt = par ^ 1;

        // h(t) fragment [n=L][k=8q+j] — issue first, latency on the chain
        const bf16x8 hfrag = *(const bf16x8*)(&h_lds[par][L * 40 + q * 8]);

        // convert x(t+1) (waits vmcnt for ra/rb under the ds_read's shadow)
        bf16x8 xfn;
        {
            u32x4 u;
            u[0] = pack_bf2(ra.x, ra.y); u[1] = pack_bf2(ra.z, ra.w);
            u[2] = pack_bf2(rb.x, rb.y); u[3] = pack_bf2(rb.z, rb.w);
            xfn = *(const bf16x8*)&u;
        }
        // issue x(t+2) — stays in flight ACROSS the barrier (no vmcnt drain)
        int tn2 = t + 2; if (tn2 > T_LEN - 1) tn2 = T_LEN - 1;
        ra = xbase[2 * tn2]; rb = xbase[2 * tn2 + 1];

        // recurrence MFMA (chain) + next-step zx (off-chain)
        const f32x4 acc = __builtin_amdgcn_mfma_f32_16x16x32_bf16(whh_f, hfrag, zx, 0, 0, 0);
        zx = __builtin_amdgcn_mfma_f32_16x16x32_bf16(wih_f, xfn, bias, 0, 0, 0);

        // activation: regs r = (i, f, g2, o); g rows pre-doubled.
        // sig(a)*tanh(b) = (1-eb)*rcp((1+ea)(1+eb)); only c-exp clamped.
        {
            const float ei = __builtin_amdgcn_exp2f(-acc[0]);
            const float ef = __builtin_amdgcn_exp2f(-acc[1]);
            const float eg = __builtin_amdgcn_exp2f(-acc[2]);
            const float eo = __builtin_amdgcn_exp2f(-acc[3]);
            const float fv = __builtin_amdgcn_rcpf(1.f + ef);
            const float ig = (1.f - eg) * __builtin_amdgcn_rcpf((1.f + ei) * (1.f + eg));
            c = fmaf(fv, c, ig);
            const float ec = __builtin_amdgcn_exp2f(fminf(c * (-2.f * LOG2E), 40.f));
            const float hv = (1.f - ec) * __builtin_amdgcn_rcpf((1.f + eo) * (1.f + ec));
            h_lds[nxt][L * 40 + hw_off] = f2bf_fast(hv);
        }

        // barrier WITHOUT vmcnt drain: only LDS must be visible.
        asm volatile("s_waitcnt lgkmcnt(0)" ::: "memory");
        __builtin_amdgcn_s_barrier();
        asm volatile("" ::: "memory");   // fence: no LDS read hoists above
    }

    // h(T) lives in buf[(255+1)&1] = buf[0]
    if (tid < 16) {
        float s = b_out[0];
#pragma unroll
        for (int k = 0; k < 32; ++k) s = fmaf(bf2f(h_lds[0][tid * 40 + k]), W_out[k], s);
        out[row0 + tid] = s;
    }
}

extern "C" void kernel_launch(void* const* d_in, const int* in_sizes, int n_in,
                              void* d_out, int out_size, void* d_ws, size_t ws_size,
                              hipStream_t stream) {
    const float* x     = (const float*)d_in[0];
    const float* W_ih  = (const float*)d_in[1];
    const float* W_hh  = (const float*)d_in[2];
    const float* b_ih  = (const float*)d_in[3];
    const float* b_hh  = (const float*)d_in[4];
    const float* W_out = (const float*)d_in[5];
    const float* b_out = (const float*)d_in[6];
    float* out = (float*)d_out;

    const int B = in_sizes[0] / (T_LEN * 8);  // 4096
    const int tiles = B / 16;                 // 256 blocks, one per CU
    lstm_kernel<<<tiles, 512, 0, stream>>>(x, W_ih, W_hh, b_ih, b_hh, W_out, b_out, out);
}

// Round 6
// 145.195 us; speedup vs baseline: 1.3079x; 1.3079x over previous
//
#include <hip/hip_runtime.h>

// LSTM: B=4096, T=256, I=8, H=32, O=1, fp32 in/out, bf16 MFMA compute.
// R11 = R7 exact restore (best measured: 74.5 us, 700 cyc/step) + two
// zero-risk micros: (1) t-loop split at the restage boundary -> no per-step
// branch; (2) peeled t=255 -> no tn clamp in loop, dead final xfrag/zx
// removed. Structure log: R8 (2 blocks/CU, dup lanes) 950 cyc/step — co-
// residency cannot compress the serial chain; R9 (4 waves, 2 val/lane) 775
// — trans ~8-9 cyc/instr, on-chain; R10 (global x per step) 1220 — HBM
// latency on-chain. Chain floor ~500 cyc: barrier + ds_read(120) + MFMA(40)
// + act depth(~140) + per-SIMD trans issue(~64) + write/wait + skew.
// 256 blocks (1/CU) x 8 waves. Block owns 16 batch rows; wave w owns hidden
// j = 4w + q (ONE (m,j) value per lane) via weight-row permutation
//   fr -> n = 32*(fr&3) + 4w + (fr>>2)   (weights are the MFMA FIRST operand)
// so lane (q,L) accum reg r = gate r at (m=L, j=4w+q): c/h update fully
// in-register, 8 trans/lane/step. x staged in LDS as bf16 in two 128-step
// chunks (zero global ops in the steady-state loop -> barrier drains only
// lgkmcnt). Gate-g rows pre-scaled by 2*log2e (others log2e).

#define T_LEN   256
#define HALF_T  128
#define XSTRIDE 130   // shorts per timestep row (16 L x 8 bf16 + 2 pad)
#define LOG2E   1.4426950408889634f

typedef short bf16x8 __attribute__((ext_vector_type(8)));
typedef float f32x4  __attribute__((ext_vector_type(4)));
typedef unsigned u32x4 __attribute__((ext_vector_type(4)));

static __device__ inline short f2bf_rne(float f) {          // one-time (weights)
    union { float f; unsigned u; } v; v.f = f;
    unsigned u = v.u;
    return (short)((u + 0x7FFFu + ((u >> 16) & 1u)) >> 16);
}
static __device__ inline short f2bf_fast(float f) {         // round-half-up
    union { float f; unsigned u; } v; v.f = f;
    return (short)((v.u + 0x8000u) >> 16);
}
static __device__ inline unsigned pack_bf2(float a, float b) {  // low=a, high=b
    union { float f; unsigned u; } x, y; x.f = a; y.f = b;
    return ((x.u + 0x8000u) >> 16) | ((y.u + 0x8000u) & 0xFFFF0000u);
}
static __device__ inline float bf2f(short s) {
    union { unsigned u; float f; } v;
    v.u = ((unsigned)(unsigned short)s) << 16;
    return v.f;
}

__global__ __launch_bounds__(512, 2) void lstm_kernel(
    const float* __restrict__ x, const float* __restrict__ W_ih,
    const float* __restrict__ W_hh, const float* __restrict__ b_ih,
    const float* __restrict__ b_hh, const float* __restrict__ W_out,
    const float* __restrict__ b_out, float* __restrict__ out)
{
    // x chunk: [t_local(0..127)][L(0..15)][8] bf16 (conflict-free: dword
    // stride 65/t, 4/L; loop reads are 4-lane broadcasts of 16 addresses)
    __shared__ __attribute__((aligned(16))) short xl[HALF_T * XSTRIDE];
    // h double buffer: [buf][m(0..15)][k(0..31)] bf16, row stride 40 shorts
    __shared__ __attribute__((aligned(16))) short h_lds[2][16 * 40];

    const int tid  = threadIdx.x;
    const int w    = tid >> 6;        // wave 0..7 -> owns j = 4w + q
    const int lane = tid & 63;
    const int L    = lane & 15;       // batch row within tile / frag row
    const int q    = lane >> 4;       // quad
    const int row0 = blockIdx.x * 16;
    const float4* xv = (const float4*)x;

    // ---- one-time: weight fragments (FIRST-operand layout [row=L][k=8q+j]) ----
    // row fr=L holds W row n = 32*(L&3) + 4w + (L>>2); gate = L&3,
    // scaled by log2e (gate-g rows: 2*log2e, folding tanh's factor 2).
    const int   n  = 32 * (L & 3) + 4 * w + (L >> 2);
    const float sc = ((L & 3) == 2 ? 2.f * LOG2E : LOG2E);
    bf16x8 whh_f, wih_f = (bf16x8){0,0,0,0,0,0,0,0};
    {
        const float* src = W_hh + n * 32 + q * 8;
#pragma unroll
        for (int j = 0; j < 8; ++j) whh_f[j] = f2bf_rne(src[j] * sc);
        if (q == 0) {                              // only k=0..7 exist (I=8)
            const float* s2 = W_ih + n * 8;
#pragma unroll
            for (int j = 0; j < 8; ++j) wih_f[j] = f2bf_rne(s2[j] * sc);
        }
    }
    // bias in C-layout: reg r -> row fr=4q+r -> n_r = 32r + 4w + q
    f32x4 bias;
#pragma unroll
    for (int r = 0; r < 4; ++r) {
        const int   nr = 32 * r + 4 * w + q;
        const float sr = (r == 2 ? 2.f * LOG2E : LOG2E);
        bias[r] = (b_ih[nr] + b_hh[nr]) * sr;
    }

    // zero h(0) buffer
    for (int i = tid; i < 16 * 40; i += 512) h_lds[0][i] = 0;

    // ---- stage chunk 0 (t in [0,128)) into xl ----
    // idx = tid + 512*it: L2 = idx>>7, tl = idx&127; 32 B/lane coalesced.
#pragma unroll
    for (int it = 0; it < 4; ++it) {
        const int idx = tid + (it << 9);
        const int L2  = idx >> 7;
        const int tl  = idx & (HALF_T - 1);
        const float4* srcp = xv + ((size_t)(row0 + L2) * T_LEN + tl) * 2;
        const float4 a = srcp[0], b = srcp[1];
        u32x4 u;
        u[0] = pack_bf2(a.x, a.y); u[1] = pack_bf2(a.z, a.w);
        u[2] = pack_bf2(b.x, b.y); u[3] = pack_bf2(b.z, b.w);
        *(u32x4*)(&xl[tl * XSTRIDE + L2 * 8]) = u;
    }
    __syncthreads();

    // zx(0) from x(0)
    f32x4 zx;
    {
        const bf16x8 xf0 = *(const bf16x8*)(&xl[L * 8]);
        zx = __builtin_amdgcn_mfma_f32_16x16x32_bf16(wih_f, xf0, bias, 0, 0, 0);
    }

    float c = 0.f;
    const int hw_off = 4 * w + q;      // this lane's j

    // One steady-state step: read h(t), MFMA, act, store h(t+1), read x(tn)
    // early so its latency hides under act (R7-proven order), barrier.
#define LSTM_STEP(T_, TN_)                                                      \
    {                                                                           \
        const int par = (T_) & 1, nxt = par ^ 1;                                \
        const bf16x8 hfrag = *(const bf16x8*)(&h_lds[par][L * 40 + q * 8]);     \
        const bf16x8 xfrag = *(const bf16x8*)(                                  \
            &xl[((TN_) & (HALF_T - 1)) * XSTRIDE + L * 8]);                     \
        const f32x4 acc =                                                       \
            __builtin_amdgcn_mfma_f32_16x16x32_bf16(whh_f, hfrag, zx, 0, 0, 0); \
        zx = __builtin_amdgcn_mfma_f32_16x16x32_bf16(wih_f, xfrag, bias, 0, 0, 0);\
        const float ei = __builtin_amdgcn_exp2f(-acc[0]);                       \
        const float ef = __builtin_amdgcn_exp2f(-acc[1]);                       \
        const float eg = __builtin_amdgcn_exp2f(-acc[2]);                       \
        const float eo = __builtin_amdgcn_exp2f(-acc[3]);                       \
        const float fv = __builtin_amdgcn_rcpf(1.f + ef);                       \
        const float ig = (1.f - eg) * __builtin_amdgcn_rcpf((1.f + ei) * (1.f + eg)); \
        c = fmaf(fv, c, ig);                                                    \
        const float ec = __builtin_amdgcn_exp2f(fminf(c * (-2.f * LOG2E), 40.f));\
        const float hv = (1.f - ec) * __builtin_amdgcn_rcpf((1.f + eo) * (1.f + ec)); \
        h_lds[nxt][L * 40 + hw_off] = f2bf_fast(hv);                            \
        __syncthreads();                                                        \
    }

    // ---- first half: t = 0..126, xfrag slots 1..127 all in chunk 0 ----
#pragma unroll 2
    for (int t = 0; t < HALF_T - 1; ++t) LSTM_STEP(t, t + 1)

    // ---- restage chunk 1 (t in [128,256)); prior reads drained by the
    //      t=126 barrier ----
#pragma unroll
    for (int it = 0; it < 4; ++it) {
        const int idx = tid + (it << 9);
        const int L2  = idx >> 7;
        const int tl  = idx & (HALF_T - 1);
        const float4* srcp = xv + ((size_t)(row0 + L2) * T_LEN + HALF_T + tl) * 2;
        const float4 a = srcp[0], b = srcp[1];
        u32x4 u;
        u[0] = pack_bf2(a.x, a.y); u[1] = pack_bf2(a.z, a.w);
        u[2] = pack_bf2(b.x, b.y); u[3] = pack_bf2(b.z, b.w);
        *(u32x4*)(&xl[tl * XSTRIDE + L2 * 8]) = u;
    }
    __syncthreads();   // one-time vm drain; loop stays vm-free

    // ---- second half: t = 127..254, xfrag slots (t+1)&127 in chunk 1 ----
#pragma unroll 2
    for (int t = HALF_T - 1; t < T_LEN - 1; ++t) LSTM_STEP(t, t + 1)

    // ---- peeled t = 255: no xfrag/zx (dead), store h(T) into buf 0 ----
    {
        const int par = (T_LEN - 1) & 1, nxt = par ^ 1;   // 1 -> 0
        const bf16x8 hfrag = *(const bf16x8*)(&h_lds[par][L * 40 + q * 8]);
        const f32x4 acc =
            __builtin_amdgcn_mfma_f32_16x16x32_bf16(whh_f, hfrag, zx, 0, 0, 0);
        const float ei = __builtin_amdgcn_exp2f(-acc[0]);
        const float ef = __builtin_amdgcn_exp2f(-acc[1]);
        const float eg = __builtin_amdgcn_exp2f(-acc[2]);
        const float eo = __builtin_amdgcn_exp2f(-acc[3]);
        const float fv = __builtin_amdgcn_rcpf(1.f + ef);
        const float ig = (1.f - eg) * __builtin_amdgcn_rcpf((1.f + ei) * (1.f + eg));
        c = fmaf(fv, c, ig);
        const float ec = __builtin_amdgcn_exp2f(fminf(c * (-2.f * LOG2E), 40.f));
        const float hv = (1.f - ec) * __builtin_amdgcn_rcpf((1.f + eo) * (1.f + ec));
        h_lds[nxt][L * 40 + hw_off] = f2bf_fast(hv);
        __syncthreads();
    }
#undef LSTM_STEP

    // h(T) lives in buf[0]
    if (tid < 16) {
        float s = b_out[0];
#pragma unroll
        for (int k = 0; k < 32; ++k) s = fmaf(bf2f(h_lds[0][tid * 40 + k]), W_out[k], s);
        out[row0 + tid] = s;
    }
}

extern "C" void kernel_launch(void* const* d_in, const int* in_sizes, int n_in,
                              void* d_out, int out_size, void* d_ws, size_t ws_size,
                              hipStream_t stream) {
    const float* x     = (const float*)d_in[0];
    const float* W_ih  = (const float*)d_in[1];
    const float* W_hh  = (const float*)d_in[2];
    const float* b_ih  = (const float*)d_in[3];
    const float* b_hh  = (const float*)d_in[4];
    const float* W_out = (const float*)d_in[5];
    const float* b_out = (const float*)d_in[6];
    float* out = (float*)d_out;

    const int B = in_sizes[0] / (T_LEN * 8);  // 4096
    const int tiles = B / 16;                 // 256 blocks, one per CU
    lstm_kernel<<<tiles, 512, 0, stream>>>(x, W_ih, W_hh, b_ih, b_hh, W_out, b_out, out);
}